// Round 2
// baseline (4594.433 us; speedup 1.0000x reference)
//
#include <hip/hip_runtime.h>
#include <math.h>

#define KSTEPS  256
#define DMODEL  1024
#define NLAYER  4
#define ROWS    2048          // 2*D rows of xh
#define NTHREADS 512
#define JPB     16            // output columns per block
#define SEQBUF_SZ (5*KSTEPS*DMODEL)   // floats: seqbuf[5][256][1024]
#define FLAG_STRIDE 32        // ints (128B) per flag
#define TIME_CAP 100000000LL  // ~1s at 100MHz s_memrealtime: bounded-failure backstop

__device__ __forceinline__ float ld_agent(const float* p) {
  return __hip_atomic_load(p, __ATOMIC_RELAXED, __HIP_MEMORY_SCOPE_AGENT);
}
__device__ __forceinline__ void st_agent(float* p, float v) {
  __hip_atomic_store(p, v, __ATOMIC_RELAXED, __HIP_MEMORY_SCOPE_AGENT);
}

__global__ void cfc_init_flags(int* flagbase) {
  int i = blockIdx.x * blockDim.x + threadIdx.x;
  if (i < 16384) flagbase[i] = 0;
}

__global__ __launch_bounds__(NTHREADS, 2)
void cfc_main(const float* __restrict__ sensor_vals,   // [256][3]
              const float* __restrict__ sensor_pos,    // [256][2]
              const float* __restrict__ Bm,            // [2][256]
              const float* __restrict__ proj_w,        // [515][1024]
              const float* __restrict__ proj_b,        // [1024]
              const float* __restrict__ ff1_w, const float* __restrict__ ff1_b,
              const float* __restrict__ ff2_w, const float* __restrict__ ff2_b,
              const float* __restrict__ ta_w,  const float* __restrict__ ta_b,
              const float* __restrict__ tb_w,  const float* __restrict__ tb_b,
              float* __restrict__ out,                 // [1024]
              float* __restrict__ ws)
{
  __shared__ float smem[16384];          // 64KB: weight slab / partials union
  float* dots = smem + 13056;            // 48 floats, beyond partial region

  const long long tstart = __builtin_amdgcn_s_memrealtime();

  const int tid   = threadIdx.x;
  const int bid   = blockIdx.x;
  const int layer = bid >> 6;            // 0..3
  const int slot  = bid & 63;            // 0..63
  const int rg    = tid & 255;           // rowgroup: rows rg*8..rg*8+7 of xh
  const int hh    = tid >> 8;            // dot half: cols hh*24..hh*24+23
  const int j0    = slot * JPB;

  float* seq = ws;                                   // seqbuf[5][256][1024]
  int* initflags = (int*)(ws + SEQBUF_SZ);           // [256] stride 32
  int* flags     = initflags + 256 * FLAG_STRIDE;    // [4][64] stride 32

  // ---------------- phase 0: seq0 = RFF-proj (all 256 blocks, 4 cols each) ----
  {
    int t  = tid & 255;
    int jp = tid >> 8;                 // 0/1 -> two j's each
    int jj = bid * 4 + jp * 2;
    float p0 = sensor_pos[t*2+0], p1 = sensor_pos[t*2+1];
    float a0 = 0.f, a1 = 0.f;
    for (int r = 0; r < 256; ++r) {
      float pr = p0 * Bm[r] + p1 * Bm[256 + r];
      float sn, cs;
      __sincosf(pr, &sn, &cs);
      a0 += cs * proj_w[r*1024 + jj]     + sn * proj_w[(256+r)*1024 + jj];
      a1 += cs * proj_w[r*1024 + jj + 1] + sn * proj_w[(256+r)*1024 + jj + 1];
    }
    for (int i = 0; i < 3; ++i) {
      float v = sensor_vals[t*3 + i];
      a0 += v * proj_w[(512+i)*1024 + jj];
      a1 += v * proj_w[(512+i)*1024 + jj + 1];
    }
    a0 += proj_b[jj]; a1 += proj_b[jj + 1];
    st_agent(&seq[t*DMODEL + jj],     a0);
    st_agent(&seq[t*DMODEL + jj + 1], a1);
    __syncthreads();
    if (tid == 0)
      __hip_atomic_store(&initflags[bid*FLAG_STRIDE], 1, __ATOMIC_RELEASE, __HIP_MEMORY_SCOPE_AGENT);
  }

  // ---------------- phase 1: load this layer's weights into VGPRs ------------
  // w[m][jl][k]: m=0:ff1, 1:ff2, 2:(tb - ta); jl: local col (hh*8+jl); k: row rg*8+k
  float w[3][8][8];
  const float* mats[4] = { ff1_w + (size_t)layer*ROWS*DMODEL,
                           ff2_w + (size_t)layer*ROWS*DMODEL,
                           ta_w  + (size_t)layer*ROWS*DMODEL,
                           tb_w  + (size_t)layer*ROWS*DMODEL };
  for (int p = 0; p < 4; ++p) {
    for (int hf = 0; hf < 2; ++hf) {
      __syncthreads();
      // stage half-slab col-major swizzled: smem[c*1024 + (rl ^ ((c&3)<<3))]
      const float* W = mats[p];
      for (int i = 0; i < 16; ++i) {
        int fp = i*512 + tid;            // 0..8191 pair index
        int f0 = fp * 2;
        int rl = f0 >> 4;                // 0..1023 local row
        int c  = f0 & 15;                // even col
        float2 v = *(const float2*)&W[(size_t)(hf*1024 + rl)*DMODEL + j0 + c];
        smem[(c  )*1024 + (rl ^ (((c  )&3)<<3))] = v.x;
        smem[(c+1)*1024 + (rl ^ (((c+1)&3)<<3))] = v.y;
      }
      __syncthreads();
      if ((rg >> 7) == hf) {
        int rl = (rg & 127) * 8;
        #pragma unroll
        for (int jl = 0; jl < 8; ++jl) {
          int c  = hh*8 + jl;
          int xr = (c & 3) << 3;
          #pragma unroll
          for (int k = 0; k < 8; ++k) {
            float v = smem[c*1024 + ((rl + k) ^ xr)];
            if      (p == 0) w[0][jl][k] = v;
            else if (p == 1) w[1][jl][k] = v;
            else if (p == 2) w[2][jl][k] = -v;
            else             w[2][jl][k] += v;
          }
        }
      }
    }
  }
  // biases for finalize threads
  float b1 = 0.f, b2 = 0.f, bc = 0.f;
  if (tid < 16) {
    int j = j0 + tid;
    b1 = ff1_b[layer*DMODEL + j];
    b2 = ff2_b[layer*DMODEL + j];
    bc = tb_b[layer*DMODEL + j] - ta_b[layer*DMODEL + j];
  }

  // ---------------- wait for seq0 (layer 0 only) ------------------------------
  if (layer == 0) {
    if (tid < 64) {
      for (;;) {
        int ok = 1;
        for (int q = 0; q < 4; ++q) {
          int v = __hip_atomic_load(&initflags[(tid + q*64)*FLAG_STRIDE],
                                    __ATOMIC_RELAXED, __HIP_MEMORY_SCOPE_AGENT);
          ok &= (v != 0);
        }
        if (__all(ok)) break;
        if (__builtin_amdgcn_s_memrealtime() - tstart > TIME_CAP) break;
      }
      __threadfence();
    }
  }
  __syncthreads();

  // ---------------- phase 2: wavefront-pipelined scan -------------------------
  float* xin_base  = seq + (size_t)layer     * KSTEPS * DMODEL;  // prev layer out
  float* xout_base = seq + (size_t)(layer+1) * KSTEPS * DMODEL;  // this layer out
  int* ownflags  = flags + layer * 64 * FLAG_STRIDE;
  int* prevflags = flags + (layer-1) * 64 * FLAG_STRIDE;

  for (int t = 0; t < KSTEPS; ++t) {
    // ---- poll: own peers >= t (h(t-1) ready), prev layer >= t+1 (x(t) ready)
    if (tid < 64) {
      for (;;) {
        int own = __hip_atomic_load(&ownflags[tid*FLAG_STRIDE],
                                    __ATOMIC_RELAXED, __HIP_MEMORY_SCOPE_AGENT);
        int ok = (own >= t);
        if (layer > 0) {
          int pv = __hip_atomic_load(&prevflags[tid*FLAG_STRIDE],
                                     __ATOMIC_RELAXED, __HIP_MEMORY_SCOPE_AGENT);
          ok &= (pv >= t + 1);
        }
        if (__all(ok)) break;
        if (__builtin_amdgcn_s_memrealtime() - tstart > TIME_CAP) break;
      }
      __threadfence();
    }
    __syncthreads();

    // ---- load this thread's 8 xh rows (agent-coherent)
    float xh[8];
    if (rg < 128) {
      const float* src = xin_base + (size_t)t*DMODEL + rg*8;
      #pragma unroll
      for (int k = 0; k < 8; ++k) xh[k] = ld_agent(&src[k]);
    } else if (t == 0) {
      #pragma unroll
      for (int k = 0; k < 8; ++k) xh[k] = 0.f;
    } else {
      const float* src = xout_base + (size_t)(t-1)*DMODEL + (rg-128)*8;
      #pragma unroll
      for (int k = 0; k < 8; ++k) xh[k] = ld_agent(&src[k]);
    }

    // ---- 192 FMA into 24 partials, write to LDS [c=48][rg pad 272]
    #pragma unroll
    for (int m = 0; m < 3; ++m) {
      float acc[8];
      #pragma unroll
      for (int jl = 0; jl < 8; ++jl) {
        float a = 0.f;
        #pragma unroll
        for (int k = 0; k < 8; ++k) a += xh[k] * w[m][jl][k];
        acc[jl] = a;
      }
      #pragma unroll
      for (int jl = 0; jl < 8; ++jl) {
        int c = hh*24 + m*8 + jl;
        smem[c*272 + rg] = acc[jl];
      }
    }
    __syncthreads();

    // ---- stage2 reduce: 48 dots x 8 lanes, interleaved float4 chunks
    if (tid < 384) {
      int c = tid >> 3, s = tid & 7;
      float sum = 0.f;
      #pragma unroll
      for (int q = 0; q < 8; ++q) {
        int ch = s + 8*q;
        float4 v = *(const float4*)&smem[c*272 + ch*4];
        sum += v.x + v.y + v.z + v.w;
      }
      sum += __shfl_xor(sum, 1);
      sum += __shfl_xor(sum, 2);
      sum += __shfl_xor(sum, 4);
      if (s == 0) dots[c] = sum;
    }
    __syncthreads();

    // ---- finalize 16 outputs
    if (tid < 16) {
      int h  = tid >> 3, jl = tid & 7;
      float s1 = dots[h*24 +  0 + jl] + b1;
      float s2 = dots[h*24 +  8 + jl] + b2;
      float sg = dots[h*24 + 16 + jl] + bc;
      float f1 = tanhf(s1);
      float f2 = tanhf(s2);
      float g  = 1.f / (1.f + __expf(-sg));
      float hn = g * f1 + (1.f - g) * f2;
      int j = j0 + tid;
      st_agent(&xout_base[(size_t)t*DMODEL + j], hn);
      if (layer == NLAYER-1 && t == KSTEPS-1) out[j] = hn;
    }
    __syncthreads();
    if (tid == 0)
      __hip_atomic_store(&ownflags[slot*FLAG_STRIDE], t + 1,
                         __ATOMIC_RELEASE, __HIP_MEMORY_SCOPE_AGENT);
  }
}

extern "C" void kernel_launch(void* const* d_in, const int* in_sizes, int n_in,
                              void* d_out, int out_size, void* d_ws, size_t ws_size,
                              hipStream_t stream) {
  const float* sensor_vals = (const float*)d_in[0];
  const float* sensor_pos  = (const float*)d_in[1];
  const float* Bm          = (const float*)d_in[2];
  const float* proj_w      = (const float*)d_in[3];
  const float* proj_b      = (const float*)d_in[4];
  const float* ff1_w       = (const float*)d_in[5];
  const float* ff1_b       = (const float*)d_in[6];
  const float* ff2_w       = (const float*)d_in[7];
  const float* ff2_b       = (const float*)d_in[8];
  const float* ta_w        = (const float*)d_in[9];
  const float* ta_b        = (const float*)d_in[10];
  const float* tb_w        = (const float*)d_in[11];
  const float* tb_b        = (const float*)d_in[12];
  float* ws  = (float*)d_ws;
  int* flagbase = (int*)(ws + SEQBUF_SZ);

  cfc_init_flags<<<16, 1024, 0, stream>>>(flagbase);
  cfc_main<<<256, NTHREADS, 0, stream>>>(sensor_vals, sensor_pos, Bm,
                                         proj_w, proj_b,
                                         ff1_w, ff1_b, ff2_w, ff2_b,
                                         ta_w, ta_b, tb_w, tb_b,
                                         (float*)d_out, ws);
}

// Round 4
// 2187.557 us; speedup vs baseline: 2.1003x; 2.1003x over previous
//
#include <hip/hip_runtime.h>
#include <math.h>

#define KSTEPS  256
#define DMODEL  1024
#define NLAYER  4
#define NTHREADS 512
#define JPB     16
#define SEQ0_FLOATS (KSTEPS*DMODEL)            // 1 MB
#define INITFLAG_INTS (256*32)                 // 32 KB
#define REC_OFF_FLOATS (SEQ0_FLOATS + INITFLAG_INTS)
#define REC_ULL ((size_t)NLAYER*KSTEPS*DMODEL) // 1,048,576 packets = 8 MB
#define WS_NEED_BYTES ((size_t)REC_OFF_FLOATS*4 + REC_ULL*8)
#define TIME_CAP 10000000LL                    // ~100ms at 100MHz s_memrealtime

typedef float f32x4 __attribute__((ext_vector_type(4)));
typedef unsigned long long u64;

__device__ __forceinline__ u64 ld_pkt(const u64* p) {
  return __hip_atomic_load(p, __ATOMIC_RELAXED, __HIP_MEMORY_SCOPE_AGENT);
}
__device__ __forceinline__ void st_pkt(u64* p, u64 v) {
  __hip_atomic_store(p, v, __ATOMIC_RELAXED, __HIP_MEMORY_SCOPE_AGENT);
}
__device__ __forceinline__ float ld_agent(const float* p) {
  return __hip_atomic_load(p, __ATOMIC_RELAXED, __HIP_MEMORY_SCOPE_AGENT);
}
__device__ __forceinline__ void st_agent(float* p, float v) {
  __hip_atomic_store(p, v, __ATOMIC_RELAXED, __HIP_MEMORY_SCOPE_AGENT);
}

// blocks 0..1023 zero rec (1 packet/thread); block 1024 zeroes initflags
__global__ void cfc_init(int* initflags, u64* rec) {
  if (blockIdx.x < 1024) {
    rec[(size_t)blockIdx.x * 1024 + threadIdx.x] = 0ULL;
  } else {
    int j = threadIdx.x;
    #pragma unroll
    for (int q = 0; q < 8; ++q) initflags[j * 8 + q] = 0;
  }
}

__global__ __launch_bounds__(NTHREADS, 1)
void cfc_main(const float* __restrict__ sensor_vals,   // [256][3]
              const float* __restrict__ sensor_pos,    // [256][2]
              const float* __restrict__ Bm,            // [2][256]
              const float* __restrict__ proj_w,        // [515][1024]
              const float* __restrict__ proj_b,        // [1024]
              const float* __restrict__ ff1_w, const float* __restrict__ ff1_b,
              const float* __restrict__ ff2_w, const float* __restrict__ ff2_b,
              const float* __restrict__ ta_w,  const float* __restrict__ ta_b,
              const float* __restrict__ tb_w,  const float* __restrict__ tb_b,
              float* __restrict__ out,                 // [1024]
              float* __restrict__ ws)
{
  __shared__ float smem[16384];          // weight staging / reduce union (64KB)
  float* dots = smem + 3584;             // 48 floats, after [64][56] region

  const long long tstart = __builtin_amdgcn_s_memrealtime();
  const int tid   = threadIdx.x;
  const int bid   = blockIdx.x;
  const int layer = bid >> 6;            // 0..3
  const int slot  = bid & 63;            // 0..63
  const int rp    = tid;                 // owns xh rows {2rp, 2rp+1}
  const int j0    = slot * JPB;

  float* seq0    = ws;                                  // [256][1024]
  int* initflags = (int*)(ws + SEQ0_FLOATS);            // [256] stride 32
  u64* rec       = (u64*)(ws + REC_OFF_FLOATS);         // [4][256][1024] packets

  // ---------------- phase 0: seq0 = RFF-proj (each block: 4 cols, all t) -----
  {
    int t  = tid & 255;
    int jp = tid >> 8;
    int jj = bid * 4 + jp * 2;
    float p0 = sensor_pos[t*2+0], p1 = sensor_pos[t*2+1];
    float a0 = 0.f, a1 = 0.f;
    for (int r = 0; r < 256; ++r) {
      float pr = p0 * Bm[r] + p1 * Bm[256 + r];
      float sn, cs;
      __sincosf(pr, &sn, &cs);
      a0 += cs * proj_w[r*1024 + jj]     + sn * proj_w[(256+r)*1024 + jj];
      a1 += cs * proj_w[r*1024 + jj + 1] + sn * proj_w[(256+r)*1024 + jj + 1];
    }
    for (int i = 0; i < 3; ++i) {
      float v = sensor_vals[t*3 + i];
      a0 += v * proj_w[(512+i)*1024 + jj];
      a1 += v * proj_w[(512+i)*1024 + jj + 1];
    }
    a0 += proj_b[jj]; a1 += proj_b[jj + 1];
    st_agent(&seq0[t*DMODEL + jj],     a0);
    st_agent(&seq0[t*DMODEL + jj + 1], a1);
    __syncthreads();
    if (tid == 0)
      __hip_atomic_store(&initflags[bid*32], 1, __ATOMIC_RELEASE, __HIP_MEMORY_SCOPE_AGENT);
  }

  // ---------------- phase 1: weights into VGPRs ------------------------------
  // thread rp: wx = x-rows {2rp,2rp+1}, wh = h-rows {2rp,2rp+1}, 16 cols, 3 mats
  float wx[3][16][2], wh[3][16][2];
  {
    const float* mats[4] = { ff1_w + (size_t)layer*2048*DMODEL,
                             ff2_w + (size_t)layer*2048*DMODEL,
                             ta_w  + (size_t)layer*2048*DMODEL,
                             tb_w  + (size_t)layer*2048*DMODEL };
    #pragma unroll
    for (int ph = 0; ph < 8; ++ph) {     // p = ph>>1 (mat), hf = ph&1 (row half)
      const int p  = ph >> 1;
      const int hf = ph & 1;
      __syncthreads();
      const float* W = mats[p];
      for (int i = 0; i < 16; ++i) {
        int fp = i*512 + tid;
        int f0 = fp * 2;
        int rl = f0 >> 4;
        int c  = f0 & 15;
        float2 v = *(const float2*)&W[(size_t)(hf*1024 + rl)*DMODEL + j0 + c];
        smem[(c  )*1024 + (rl ^ (((c  )&3)<<3))] = v.x;
        smem[(c+1)*1024 + (rl ^ (((c+1)&3)<<3))] = v.y;
      }
      __syncthreads();
      int r0 = 2 * rp;
      #pragma unroll
      for (int cl = 0; cl < 16; ++cl) {
        int xr = (cl & 3) << 3;
        float v0 = smem[cl*1024 + ( r0      ^ xr)];
        float v1 = smem[cl*1024 + ((r0 + 1) ^ xr)];
        if      (ph == 0) { wx[0][cl][0] = v0;  wx[0][cl][1] = v1; }
        else if (ph == 1) { wh[0][cl][0] = v0;  wh[0][cl][1] = v1; }
        else if (ph == 2) { wx[1][cl][0] = v0;  wx[1][cl][1] = v1; }
        else if (ph == 3) { wh[1][cl][0] = v0;  wh[1][cl][1] = v1; }
        else if (ph == 4) { wx[2][cl][0] = -v0; wx[2][cl][1] = -v1; }
        else if (ph == 5) { wh[2][cl][0] = -v0; wh[2][cl][1] = -v1; }
        else if (ph == 6) { wx[2][cl][0] += v0; wx[2][cl][1] += v1; }
        else              { wh[2][cl][0] += v0; wh[2][cl][1] += v1; }
      }
    }
  }
  // biases for finalize threads (cols j0+2k, j0+2k+1)
  float b1a=0.f,b1b=0.f,b2a=0.f,b2b=0.f,bca=0.f,bcb=0.f;
  if (tid < 8) {
    int j = j0 + 2*tid;
    b1a = ff1_b[layer*DMODEL + j];     b1b = ff1_b[layer*DMODEL + j + 1];
    b2a = ff2_b[layer*DMODEL + j];     b2b = ff2_b[layer*DMODEL + j + 1];
    bca = tb_b[layer*DMODEL + j]     - ta_b[layer*DMODEL + j];
    bcb = tb_b[layer*DMODEL + j + 1] - ta_b[layer*DMODEL + j + 1];
  }

  // ---------------- wait for seq0 (layer 0 only) -----------------------------
  if (layer == 0) {
    if (tid < 64) {
      for (;;) {
        int ok = 1;
        for (int q = 0; q < 4; ++q) {
          int v = __hip_atomic_load(&initflags[(tid + q*64)*32],
                                    __ATOMIC_RELAXED, __HIP_MEMORY_SCOPE_AGENT);
          ok &= (v != 0);
        }
        if (__all(ok)) break;
        if (__builtin_amdgcn_s_memrealtime() - tstart > TIME_CAP) break;
      }
      __threadfence();   // acquire: invalidate stale L1/L2 before plain seq0 reads
    }
  }
  __syncthreads();

  // ---------------- phase 2: wavefront scan, 8B packet exchange --------------
  u64* recO = rec + (size_t)layer * KSTEPS * DMODEL;                   // own
  u64* recP = rec + (size_t)(layer > 0 ? layer-1 : 0) * KSTEPS * DMODEL; // prev

  for (int t = 0; t < KSTEPS; ++t) {
    float xv0, xv1, hv0, hv1;
    int gcnt = 0;
    const unsigned st_h = (unsigned)t;        // own-layer stamp for step t-1
    const unsigned st_x = (unsigned)(t + 1);  // prev-layer stamp for step t

    if (layer == 0) {
      // x: plain vector load from read-only seq0 (stable after acquire)
      float2 x2 = *(const float2*)&seq0[(size_t)t*DMODEL + 2*rp];
      xv0 = x2.x; xv1 = x2.y;
      if (t == 0) {
        hv0 = hv1 = 0.f;
      } else {
        const u64* pH = recO + (size_t)(t-1)*DMODEL + 2*rp;
        u64 h0, h1;
        for (;;) {
          h0 = ld_pkt(pH); h1 = ld_pkt(pH + 1);
          if ((unsigned)(h0 >> 32) == st_h && (unsigned)(h1 >> 32) == st_h) break;
          if (((++gcnt) & 63) == 0 &&
              __builtin_amdgcn_s_memrealtime() - tstart > TIME_CAP) break;
        }
        hv0 = __int_as_float((int)(unsigned)h0);
        hv1 = __int_as_float((int)(unsigned)h1);
      }
    } else {
      const u64* pX = recP + (size_t)t*DMODEL + 2*rp;
      if (t == 0) {
        u64 x0, x1;
        for (;;) {
          x0 = ld_pkt(pX); x1 = ld_pkt(pX + 1);
          if ((unsigned)(x0 >> 32) == st_x && (unsigned)(x1 >> 32) == st_x) break;
          if (((++gcnt) & 63) == 0 &&
              __builtin_amdgcn_s_memrealtime() - tstart > TIME_CAP) break;
        }
        xv0 = __int_as_float((int)(unsigned)x0);
        xv1 = __int_as_float((int)(unsigned)x1);
        hv0 = hv1 = 0.f;
      } else {
        const u64* pH = recO + (size_t)(t-1)*DMODEL + 2*rp;
        u64 x0, x1, h0, h1;
        for (;;) {
          x0 = ld_pkt(pX); x1 = ld_pkt(pX + 1);
          h0 = ld_pkt(pH); h1 = ld_pkt(pH + 1);
          if ((unsigned)(x0 >> 32) == st_x && (unsigned)(x1 >> 32) == st_x &&
              (unsigned)(h0 >> 32) == st_h && (unsigned)(h1 >> 32) == st_h) break;
          if (((++gcnt) & 63) == 0 &&
              __builtin_amdgcn_s_memrealtime() - tstart > TIME_CAP) break;
        }
        xv0 = __int_as_float((int)(unsigned)x0);
        xv1 = __int_as_float((int)(unsigned)x1);
        hv0 = __int_as_float((int)(unsigned)h0);
        hv1 = __int_as_float((int)(unsigned)h1);
      }
    }

    // ---- 192 FMA into 48 partials
    float part[3][16];
    #pragma unroll
    for (int m = 0; m < 3; ++m) {
      #pragma unroll
      for (int cl = 0; cl < 16; ++cl) {
        float a = xv0 * wx[m][cl][0];
        a = fmaf(xv1, wx[m][cl][1], a);
        a = fmaf(hv0, wh[m][cl][0], a);
        a = fmaf(hv1, wh[m][cl][1], a);
        part[m][cl] = a;
      }
    }

    // ---- butterfly over 8-lane groups (16 rows per group)
    #pragma unroll
    for (int m = 0; m < 3; ++m) {
      #pragma unroll
      for (int cl = 0; cl < 16; ++cl) {
        float v = part[m][cl];
        v += __shfl_xor(v, 1);
        v += __shfl_xor(v, 2);
        v += __shfl_xor(v, 4);
        part[m][cl] = v;
      }
    }

    // ---- group leaders write [64 groups][56] as 12 x b128
    if ((rp & 7) == 0) {
      float* dst = smem + (rp >> 3) * 56;
      #pragma unroll
      for (int m = 0; m < 3; ++m) {
        #pragma unroll
        for (int q = 0; q < 4; ++q) {
          f32x4 v4 = { part[m][4*q], part[m][4*q+1], part[m][4*q+2], part[m][4*q+3] };
          *(f32x4*)(dst + m*16 + q*4) = v4;
        }
      }
    }
    __syncthreads();

    // ---- column sums over 64 groups
    if (tid < 48) {
      float a0=0.f, a1=0.f, a2=0.f, a3=0.f;
      for (int g = 0; g < 64; g += 4) {
        a0 += smem[(g  )*56 + tid];
        a1 += smem[(g+1)*56 + tid];
        a2 += smem[(g+2)*56 + tid];
        a3 += smem[(g+3)*56 + tid];
      }
      dots[tid] = (a0 + a1) + (a2 + a3);
    }
    __syncthreads();

    // ---- finalize: 8 threads, 2 cols each, one 8B packet per col
    if (tid < 8) {
      float d10 = dots[      2*tid], d11 = dots[      2*tid + 1];
      float d20 = dots[16 +  2*tid], d21 = dots[16 +  2*tid + 1];
      float dc0 = dots[32 +  2*tid], dc1 = dots[32 +  2*tid + 1];
      float f10 = tanhf(d10 + b1a), f11 = tanhf(d11 + b1b);
      float f20 = tanhf(d20 + b2a), f21 = tanhf(d21 + b2b);
      float g0 = 1.f / (1.f + __expf(-(dc0 + bca)));
      float g1 = 1.f / (1.f + __expf(-(dc1 + bcb)));
      float h0 = g0*f10 + (1.f - g0)*f20;
      float h1 = g1*f11 + (1.f - g1)*f21;
      u64 w0 = ((u64)(unsigned)(t+1) << 32) | (unsigned)__float_as_int(h0);
      u64 w1 = ((u64)(unsigned)(t+1) << 32) | (unsigned)__float_as_int(h1);
      u64* pO = recO + (size_t)t*DMODEL + j0 + 2*tid;
      st_pkt(pO,     w0);
      st_pkt(pO + 1, w1);
      if (layer == NLAYER-1 && t == KSTEPS-1) {
        out[j0 + 2*tid] = h0; out[j0 + 2*tid + 1] = h1;
      }
    }
    // no extra barrier: dots region disjoint from next iteration's LDS writes
  }
}

extern "C" void kernel_launch(void* const* d_in, const int* in_sizes, int n_in,
                              void* d_out, int out_size, void* d_ws, size_t ws_size,
                              hipStream_t stream) {
  if (ws_size < WS_NEED_BYTES) return;   // informative fail (poisoned out), no fault

  const float* sensor_vals = (const float*)d_in[0];
  const float* sensor_pos  = (const float*)d_in[1];
  const float* Bm          = (const float*)d_in[2];
  const float* proj_w      = (const float*)d_in[3];
  const float* proj_b      = (const float*)d_in[4];
  const float* ff1_w       = (const float*)d_in[5];
  const float* ff1_b       = (const float*)d_in[6];
  const float* ff2_w       = (const float*)d_in[7];
  const float* ff2_b       = (const float*)d_in[8];
  const float* ta_w        = (const float*)d_in[9];
  const float* ta_b        = (const float*)d_in[10];
  const float* tb_w        = (const float*)d_in[11];
  const float* tb_b        = (const float*)d_in[12];
  float* ws      = (float*)d_ws;
  int* initflags = (int*)(ws + SEQ0_FLOATS);
  u64* rec       = (u64*)(ws + REC_OFF_FLOATS);

  cfc_init<<<1025, 1024, 0, stream>>>(initflags, rec);
  cfc_main<<<256, NTHREADS, 0, stream>>>(sensor_vals, sensor_pos, Bm,
                                         proj_w, proj_b,
                                         ff1_w, ff1_b, ff2_w, ff2_b,
                                         ta_w, ta_b, tb_w, tb_b,
                                         (float*)d_out, ws);
}

// Round 5
// 1337.246 us; speedup vs baseline: 3.4357x; 1.6359x over previous
//
#include <hip/hip_runtime.h>
#include <math.h>

#define KSTEPS  256
#define DMODEL  1024
#define NLAYER  4
#define NTHREADS 512
#define JPB     16
#define SEQ0_FLOATS (KSTEPS*DMODEL)            // 1 MB
#define INITFLAG_INTS (256*32)                 // 32 KB
#define REC_OFF_FLOATS (SEQ0_FLOATS + INITFLAG_INTS)
#define REC_ULL ((size_t)NLAYER*KSTEPS*DMODEL) // 8 MB of 8B packets
#define WS_NEED_BYTES ((size_t)REC_OFF_FLOATS*4 + REC_ULL*8)
#define TIME_CAP 10000000LL                    // ~100ms backstop

typedef float f32x4 __attribute__((ext_vector_type(4)));
typedef unsigned long long u64;

__device__ __forceinline__ u64 ld_pkt(const u64* p) {
  return __hip_atomic_load(p, __ATOMIC_RELAXED, __HIP_MEMORY_SCOPE_AGENT);
}
__device__ __forceinline__ void st_pkt(u64* p, u64 v) {
  __hip_atomic_store(p, v, __ATOMIC_RELAXED, __HIP_MEMORY_SCOPE_AGENT);
}
__device__ __forceinline__ void st_agent(float* p, float v) {
  __hip_atomic_store(p, v, __ATOMIC_RELAXED, __HIP_MEMORY_SCOPE_AGENT);
}

// wave64 sum via DPP (VALU pipe only); result valid in lane 63
#define DPP_STEP(v, ctrl) \
  v += __builtin_bit_cast(float, __builtin_amdgcn_update_dpp( \
        0, __builtin_bit_cast(int, v), ctrl, 0xf, 0xf, true))
__device__ __forceinline__ float wave_sum64(float v) {
  DPP_STEP(v, 0x111);  // row_shr:1
  DPP_STEP(v, 0x112);  // row_shr:2
  DPP_STEP(v, 0x114);  // row_shr:4
  DPP_STEP(v, 0x118);  // row_shr:8
  DPP_STEP(v, 0x142);  // row_bcast:15
  DPP_STEP(v, 0x143);  // row_bcast:31
  return v;
}

__device__ __forceinline__ float tanh_fast(float s) {
  float e = __expf(2.f * s);
  return 1.f - 2.f / (e + 1.f);   // inf-safe: ±1 at large |s|
}

// swizzled position for a [col][1024-row] LDS slab:
//  - 16-row chunks rotated across the column (chunk+c) for write-bank spread
//  - within-chunk 4-float groups rotated by (chunk+c)&3 so that a lane's
//    b128 reads of chunk l cover all 32 banks across the wave
__device__ __forceinline__ int wpos(int c, int row) {
  int ch = row >> 4;
  return c*1024 + (((ch + c) & 63) << 4)
       + (((row & 15) + (((ch + c) & 3) << 2)) & 15);
}

// blocks 0..1023 zero rec (1 packet/thread); block 1024 zeroes initflags
__global__ void cfc_init(int* initflags, u64* rec) {
  if (blockIdx.x < 1024) {
    rec[(size_t)blockIdx.x * 1024 + threadIdx.x] = 0ULL;
  } else {
    int j = threadIdx.x;
    #pragma unroll
    for (int q = 0; q < 8; ++q) initflags[j * 8 + q] = 0;
  }
}

__global__ __launch_bounds__(NTHREADS, 1)
void cfc_main(const float* __restrict__ sensor_vals,   // [256][3]
              const float* __restrict__ sensor_pos,    // [256][2]
              const float* __restrict__ Bm,            // [2][256]
              const float* __restrict__ proj_w,        // [515][1024]
              const float* __restrict__ proj_b,        // [1024]
              const float* __restrict__ ff1_w, const float* __restrict__ ff1_b,
              const float* __restrict__ ff2_w, const float* __restrict__ ff2_b,
              const float* __restrict__ ta_w,  const float* __restrict__ ta_b,
              const float* __restrict__ tb_w,  const float* __restrict__ tb_b,
              float* __restrict__ out,                 // [1024]
              float* __restrict__ ws)
{
  __shared__ float smem[16384];   // 64KB: weight staging; scan reuses [0,4096)

  const long long tstart = __builtin_amdgcn_s_memrealtime();
  const int tid   = threadIdx.x;
  const int bid   = blockIdx.x;
  const int layer = bid >> 6;           // 0..3
  const int slot  = bid & 63;           // 0..63
  const int w     = tid >> 6;           // wave 0..7 -> cols j0+2w, j0+2w+1
  const int lane  = tid & 63;           // lane l -> xh rows 16l..16l+15
  const int j0    = slot * JPB;

  float* seq0    = ws;                                  // [256][1024]
  int* initflags = (int*)(ws + SEQ0_FLOATS);            // [256] stride 32
  u64* rec       = (u64*)(ws + REC_OFF_FLOATS);         // [4][256][1024]

  // ---------------- phase 0: seq0 = RFF-proj (each block: 4 cols, all t) -----
  {
    int t  = tid & 255;
    int jp = tid >> 8;
    int jj = bid * 4 + jp * 2;
    float p0 = sensor_pos[t*2+0], p1 = sensor_pos[t*2+1];
    float a0 = 0.f, a1 = 0.f;
    for (int r = 0; r < 256; ++r) {
      float pr = p0 * Bm[r] + p1 * Bm[256 + r];
      float sn, cs;
      __sincosf(pr, &sn, &cs);
      a0 += cs * proj_w[r*1024 + jj]     + sn * proj_w[(256+r)*1024 + jj];
      a1 += cs * proj_w[r*1024 + jj + 1] + sn * proj_w[(256+r)*1024 + jj + 1];
    }
    for (int i = 0; i < 3; ++i) {
      float v = sensor_vals[t*3 + i];
      a0 += v * proj_w[(512+i)*1024 + jj];
      a1 += v * proj_w[(512+i)*1024 + jj + 1];
    }
    a0 += proj_b[jj]; a1 += proj_b[jj + 1];
    st_agent(&seq0[t*DMODEL + jj],     a0);
    st_agent(&seq0[t*DMODEL + jj + 1], a1);
    __syncthreads();
    if (tid == 0)
      __hip_atomic_store(&initflags[bid*32], 1, __ATOMIC_RELEASE, __HIP_MEMORY_SCOPE_AGENT);
  }

  // ---------------- phase 1: weights into VGPRs ------------------------------
  // wave w owns block-cols {2w, 2w+1}; lane owns rows 16*lane..16*lane+15
  // wx[m][cc][k]: x-row (16*lane+k); wh[m][cc][k]: h-row; m=0:ff1 1:ff2 2:(tb-ta)
  float wx[3][2][16], wh[3][2][16];
  {
    const float* mats[4] = { ff1_w + (size_t)layer*2048*DMODEL,
                             ff2_w + (size_t)layer*2048*DMODEL,
                             ta_w  + (size_t)layer*2048*DMODEL,
                             tb_w  + (size_t)layer*2048*DMODEL };
    #pragma unroll
    for (int ph = 0; ph < 8; ++ph) {    // p = ph>>1 (mat), hf = ph&1 (x/h half)
      const int p  = ph >> 1;
      const int hf = ph & 1;
      __syncthreads();
      const float* W = mats[p];
      for (int i = 0; i < 16; ++i) {
        int f0 = (i*512 + tid) * 2;
        int rl = f0 >> 4;
        int c  = f0 & 15;
        float2 v = *(const float2*)&W[(size_t)(hf*1024 + rl)*DMODEL + j0 + c];
        smem[wpos(c,   rl)] = v.x;
        smem[wpos(c+1, rl)] = v.y;
      }
      __syncthreads();
      #pragma unroll
      for (int cc = 0; cc < 2; ++cc) {
        const int c    = 2*w + cc;
        const int base = c*1024 + (((lane + c) & 63) << 4);
        #pragma unroll
        for (int q = 0; q < 4; ++q) {
          int pp = (q + lane + c) & 3;
          f32x4 v = *(const f32x4*)&smem[base + (pp << 2)];
          #pragma unroll
          for (int r = 0; r < 4; ++r) {
            const int k = 4*q + r;
            float vv = (r==0) ? v.x : (r==1) ? v.y : (r==2) ? v.z : v.w;
            if      (ph == 0) wx[0][cc][k] = vv;
            else if (ph == 1) wh[0][cc][k] = vv;
            else if (ph == 2) wx[1][cc][k] = vv;
            else if (ph == 3) wh[1][cc][k] = vv;
            else if (ph == 4) wx[2][cc][k] = -vv;
            else if (ph == 5) wh[2][cc][k] = -vv;
            else if (ph == 6) wx[2][cc][k] += vv;
            else              wh[2][cc][k] += vv;
          }
        }
      }
    }
  }
  // biases for this wave's 2 cols (wave-uniform scalar loads)
  float bb1[2], bb2[2], bbc[2];
  #pragma unroll
  for (int cc = 0; cc < 2; ++cc) {
    int j = j0 + 2*w + cc;
    bb1[cc] = ff1_b[layer*DMODEL + j];
    bb2[cc] = ff2_b[layer*DMODEL + j];
    bbc[cc] = tb_b[layer*DMODEL + j] - ta_b[layer*DMODEL + j];
  }

  // ---------------- wait for seq0 (layer 0 only) -----------------------------
  if (layer == 0) {
    if (tid < 64) {
      for (;;) {
        int ok = 1;
        for (int q = 0; q < 4; ++q) {
          int v = __hip_atomic_load(&initflags[(tid + q*64)*32],
                                    __ATOMIC_RELAXED, __HIP_MEMORY_SCOPE_AGENT);
          ok &= (v != 0);
        }
        if (__all(ok)) break;
        if (__builtin_amdgcn_s_memrealtime() - tstart > TIME_CAP) break;
      }
      __threadfence();
    }
  }
  __syncthreads();

  // ---------------- phase 2: wavefront scan ----------------------------------
  u64* recO = rec + (size_t)layer * KSTEPS * DMODEL;
  u64* recP = rec + (size_t)(layer > 0 ? layer-1 : 0) * KSTEPS * DMODEL;

  for (int t = 0; t < KSTEPS; ++t) {
    const int i0 = tid << 1;            // this thread stages cols i0, i0+1
    float hva = 0.f, hvb = 0.f, xva = 0.f, xvb = 0.f;
    if (layer == 0) {
      float2 x2 = *(const float2*)&seq0[(size_t)t*DMODEL + i0];
      xva = x2.x; xvb = x2.y;
    }
    if (t > 0 || layer > 0) {
      const u64* pH = recO + (size_t)(t-1)*DMODEL + i0;
      const u64* pX = recP + (size_t)t*DMODEL + i0;
      const unsigned sh = (unsigned)t, sx = (unsigned)(t+1);
      int cnt = 0;
      for (;;) {
        u64 h0 = 0, h1 = 0, x0 = 0, x1 = 0;
        int ok = 1;
        if (t > 0)     { h0 = ld_pkt(pH); h1 = ld_pkt(pH + 1);
                         ok &= ((unsigned)(h0 >> 32) == sh) &
                               ((unsigned)(h1 >> 32) == sh); }
        if (layer > 0) { x0 = ld_pkt(pX); x1 = ld_pkt(pX + 1);
                         ok &= ((unsigned)(x0 >> 32) == sx) &
                               ((unsigned)(x1 >> 32) == sx); }
        if (__all(ok)) {
          if (t > 0)     { hva = __int_as_float((int)(unsigned)h0);
                           hvb = __int_as_float((int)(unsigned)h1); }
          if (layer > 0) { xva = __int_as_float((int)(unsigned)x0);
                           xvb = __int_as_float((int)(unsigned)x1); }
          break;
        }
        __builtin_amdgcn_s_sleep(4);    // pace LLC poll traffic
        if (((++cnt) & 15) == 0 &&
            __builtin_amdgcn_s_memrealtime() - tstart > TIME_CAP) break;
      }
    }

    // stage h,x rows into swizzled LDS (double-buffered by t parity)
    float* hbuf = smem + (t & 1) * 2048;
    float* xbuf = hbuf + 1024;
    const int hp = wpos(0, i0);         // pair stays contiguous under swizzle
    *(float2*)&hbuf[hp] = make_float2(hva, hvb);
    *(float2*)&xbuf[hp] = make_float2(xva, xvb);
    __syncthreads();

    // gather own 16+16 values (4+4 b128, bank-spread) and accumulate
    float a[3][2] = {};
    const int base = lane << 4;
    #pragma unroll
    for (int q = 0; q < 4; ++q) {
      int pp = (q + lane) & 3;
      f32x4 vh = *(const f32x4*)&hbuf[base + (pp << 2)];
      f32x4 vx = *(const f32x4*)&xbuf[base + (pp << 2)];
      #pragma unroll
      for (int m = 0; m < 3; ++m)
        #pragma unroll
        for (int cc = 0; cc < 2; ++cc) {
          float s = a[m][cc];
          s = fmaf(vx.x, wx[m][cc][4*q+0], s);
          s = fmaf(vx.y, wx[m][cc][4*q+1], s);
          s = fmaf(vx.z, wx[m][cc][4*q+2], s);
          s = fmaf(vx.w, wx[m][cc][4*q+3], s);
          s = fmaf(vh.x, wh[m][cc][4*q+0], s);
          s = fmaf(vh.y, wh[m][cc][4*q+1], s);
          s = fmaf(vh.z, wh[m][cc][4*q+2], s);
          s = fmaf(vh.w, wh[m][cc][4*q+3], s);
          a[m][cc] = s;
        }
    }

    // wave-local DPP reduce; lane 63 finalizes this wave's 2 cols
    float r[3][2];
    #pragma unroll
    for (int m = 0; m < 3; ++m)
      #pragma unroll
      for (int cc = 0; cc < 2; ++cc)
        r[m][cc] = wave_sum64(a[m][cc]);

    if (lane == 63) {
      #pragma unroll
      for (int cc = 0; cc < 2; ++cc) {
        float f1 = tanh_fast(r[0][cc] + bb1[cc]);
        float f2 = tanh_fast(r[1][cc] + bb2[cc]);
        float g  = 1.f / (1.f + __expf(-(r[2][cc] + bbc[cc])));
        float h  = f2 + g * (f1 - f2);
        int j = j0 + 2*w + cc;
        u64 pk = ((u64)(unsigned)(t + 1) << 32) | (unsigned)__float_as_int(h);
        st_pkt(recO + (size_t)t*DMODEL + j, pk);
        if (layer == NLAYER-1 && t == KSTEPS-1) out[j] = h;
      }
    }
    // no trailing barrier: next round writes the other hbuf/xbuf parity
  }
}

extern "C" void kernel_launch(void* const* d_in, const int* in_sizes, int n_in,
                              void* d_out, int out_size, void* d_ws, size_t ws_size,
                              hipStream_t stream) {
  if (ws_size < WS_NEED_BYTES) return;  // informative fail, no fault

  const float* sensor_vals = (const float*)d_in[0];
  const float* sensor_pos  = (const float*)d_in[1];
  const float* Bm          = (const float*)d_in[2];
  const float* proj_w      = (const float*)d_in[3];
  const float* proj_b      = (const float*)d_in[4];
  const float* ff1_w       = (const float*)d_in[5];
  const float* ff1_b       = (const float*)d_in[6];
  const float* ff2_w       = (const float*)d_in[7];
  const float* ff2_b       = (const float*)d_in[8];
  const float* ta_w        = (const float*)d_in[9];
  const float* ta_b        = (const float*)d_in[10];
  const float* tb_w        = (const float*)d_in[11];
  const float* tb_b        = (const float*)d_in[12];
  float* ws      = (float*)d_ws;
  int* initflags = (int*)(ws + SEQ0_FLOATS);
  u64* rec       = (u64*)(ws + REC_OFF_FLOATS);

  cfc_init<<<1025, 1024, 0, stream>>>(initflags, rec);
  cfc_main<<<256, NTHREADS, 0, stream>>>(sensor_vals, sensor_pos, Bm,
                                         proj_w, proj_b,
                                         ff1_w, ff1_b, ff2_w, ff2_b,
                                         ta_w, ta_b, tb_w, tb_b,
                                         (float*)d_out, ws);
}